// Round 9
// baseline (279.726 us; speedup 1.0000x reference)
//
#include <hip/hip_runtime.h>
#include <math.h>

// ---------------------------------------------------------------------------
// GraphTransformerBlock: TransformerConv (4 heads x 32) + residual MLP.
// Round 9:
//  - EA permutation ELIMINATED: scatter writes only (src,eid) int2 pairs;
//    gather reads edge_attr fp32 directly (one 128B line/edge, no converts).
//  - gemm slices: 128-row tiles (64 MFMA per weight stage) + x pre-cast to
//    bf16 once in prep (shared across the 5 slices).
// ---------------------------------------------------------------------------

#define D 128
#define EDIM 32

using bf16x8 = __attribute__((ext_vector_type(8))) short;
using f32x4  = __attribute__((ext_vector_type(4))) float;
using ushort8 = __attribute__((ext_vector_type(8))) unsigned short;

__device__ inline unsigned short f2bf(float f) {
    unsigned int u = __float_as_uint(f);
    u += 0x7FFFu + ((u >> 16) & 1u);          // round-to-nearest-even
    return (unsigned short)(u >> 16);
}
__device__ inline float bf2f(unsigned short h) {
    return __uint_as_float(((unsigned int)h) << 16);
}
__device__ inline float gelu_fast(float x) {
    float x3 = x * x * x;
    float u = 0.7978845608028654f * (x + 0.044715f * x3);
    float t = 1.f - 2.f / (__expf(2.f * u) + 1.f);   // tanh(u)
    return 0.5f * x * (1.f + t);
}
// sum over aligned 4-lane quad via DPP quad_perm (all 4 lanes get the sum)
__device__ inline float quad_add(float x) {
    int a = __builtin_amdgcn_update_dpp(0, __float_as_int(x), 0xB1, 0xF, 0xF, true);
    x += __int_as_float(a);
    a = __builtin_amdgcn_update_dpp(0, __float_as_int(x), 0x4E, 0xF, 0xF, true);
    x += __int_as_float(a);
    return x;
}

// swizzled B-frag read: element (col, kk0..kk0+7) of the staged weight tile
__device__ inline bf16x8 ldsB(const unsigned short* sw, int col, int kk0) {
    return *(const bf16x8*)(sw + col * 128 + (kk0 ^ ((col & 7) << 3)));
}

// ---------------------------------------------------------------------------
// prep: blocks 0..511 -> 8 pre-swizzled bf16 weight tables
//   Wt[m][col*128 + (kk ^ ((col&7)<<3))] = W_m[kk][col]
//   m: 0=Wq 1=Wk 2=Wv 3=Wskip 4=W1 5=W2 6=WqE (inline dot) 7=WtCorr
// block 512: bqE.  blocks 513..513+HB-1: hist. blocks 513+HB..: x -> bf16.
// ---------------------------------------------------------------------------
__global__ __launch_bounds__(256) void prep_kernel(
    const float* __restrict__ Wq, const float* __restrict__ Wk,
    const float* __restrict__ Wv, const float* __restrict__ Wsk,
    const float* __restrict__ W1, const float* __restrict__ W2,
    const float* __restrict__ We, const float* __restrict__ bq,
    unsigned short* __restrict__ Wt, float* __restrict__ bqE,
    const int* __restrict__ EI, int* __restrict__ deg, int E, int HB,
    const float* __restrict__ x, unsigned short* __restrict__ XB, long xtot)
{
    if ((int)blockIdx.x >= 513 + HB) {    // x -> bf16 tail
        long i8 = ((long)(blockIdx.x - 513 - HB) * 256 + threadIdx.x) * 8;
        if (i8 + 8 <= xtot) {
            float4 a = *(const float4*)(x + i8);
            float4 b = *(const float4*)(x + i8 + 4);
            ushort8 u;
            u[0] = f2bf(a.x); u[1] = f2bf(a.y); u[2] = f2bf(a.z); u[3] = f2bf(a.w);
            u[4] = f2bf(b.x); u[5] = f2bf(b.y); u[6] = f2bf(b.z); u[7] = f2bf(b.w);
            *(ushort8*)(XB + i8) = u;
        }
        return;
    }
    if (blockIdx.x >= 513) {              // hist
        int e = (blockIdx.x - 513) * 256 + threadIdx.x;
        if (e < E) atomicAdd(&deg[EI[E + e]], 1);
        return;
    }
    int t = blockIdx.x * 256 + threadIdx.x;
    int m = t >> 14;
    int r = t & 16383;
    if (m >= 8) {                         // bqE block
        if (r < 128) {
            const int hb = r & 96, k = r & 31;
            const float* wek = We + (size_t)k * D + hb;
            float s = 0.f;
#pragma unroll 8
            for (int c = 0; c < 32; ++c) s = fmaf(bq[hb + c], wek[c], s);
            bqE[r] = s;
        }
        return;
    }
    int col = r & 127, kk = r >> 7;
    float v;
    if (m < 6) {
        const float* W = (m == 0) ? Wq : (m == 1) ? Wk : (m == 2) ? Wv
                       : (m == 3) ? Wsk : (m == 4) ? W1 : W2;
        v = W[(size_t)kk * D + col];
    } else if (m == 6) {
        const int hb = col & 96;
        const float* wqr = Wq + (size_t)kk * D + hb;
        const float* wer = We + (size_t)(col & 31) * D + hb;
        float s = 0.f;
#pragma unroll 8
        for (int c = 0; c < 32; ++c) s = fmaf(wqr[c], wer[c], s);
        v = s;
    } else {
        v = ((kk >> 5) == (col >> 5)) ? We[(size_t)(kk & 31) * D + col] : 0.f;
    }
    Wt[(size_t)m * 16384 + (size_t)col * 128 + (kk ^ ((col & 7) << 3))] = f2bf(v);
}

// ---------------------------------------------------------------------------
// hierarchical scan
// ---------------------------------------------------------------------------
__global__ __launch_bounds__(1024) void scanA(
    const int* __restrict__ deg, int* __restrict__ rowptr,
    int* __restrict__ psums, int N)
{
    __shared__ int tmp[1024];
    const int t = threadIdx.x;
    const int i = blockIdx.x * 1024 + t;
    int v = (i < N) ? deg[i] : 0;
    tmp[t] = v;
    __syncthreads();
    for (int off = 1; off < 1024; off <<= 1) {
        int add = (t >= off) ? tmp[t - off] : 0;
        __syncthreads();
        tmp[t] += add;
        __syncthreads();
    }
    if (i < N) rowptr[i + 1] = tmp[t];
    if (t == 1023) psums[blockIdx.x] = tmp[1023];
}

__global__ __launch_bounds__(1024) void scanB(int* __restrict__ psums, int nb)
{
    __shared__ int tmp[1024];
    const int t = threadIdx.x;
    int v = (t < nb) ? psums[t] : 0;
    tmp[t] = v;
    __syncthreads();
    for (int off = 1; off < 1024; off <<= 1) {
        int add = (t >= off) ? tmp[t - off] : 0;
        __syncthreads();
        tmp[t] += add;
        __syncthreads();
    }
    if (t < nb) psums[t] = tmp[t] - v;   // exclusive
}

__global__ __launch_bounds__(256) void scanC(
    int* __restrict__ rowptr, int* __restrict__ cursor,
    const int* __restrict__ psums, int N)
{
    int i = blockIdx.x * 256 + threadIdx.x;
    if (i == 0) { rowptr[0] = 0; cursor[0] = 0; }
    if (i < N) {
        int val = rowptr[i + 1] + psums[i >> 10];
        rowptr[i + 1] = val;
        if (i + 1 < N) cursor[i + 1] = val;
    }
}

// ---------------------------------------------------------------------------
// mega: blocks [0, 5*NB2) = gemm slices m=0..4 (128-row tiles, bf16 x);
//       blocks [5*NB2, +EB) = mini-scatter (src,eid) int2 per edge.
// ---------------------------------------------------------------------------
__global__ __launch_bounds__(256) void mega_gemm_scatter(
    const unsigned short* __restrict__ XB, const unsigned short* __restrict__ Wt,
    const float* __restrict__ bq, const float* __restrict__ bk,
    const float* __restrict__ bv, const float* __restrict__ bs,
    const float* __restrict__ bqE,
    unsigned short* __restrict__ QA, unsigned short* __restrict__ KV,
    float* __restrict__ S, int N, int NB2,
    const int* __restrict__ EI, int* __restrict__ cursor,
    int2* __restrict__ SE, int E)
{
    __shared__ unsigned short sw[16384];
    const int t = threadIdx.x;

    if ((int)blockIdx.x >= 5 * NB2) {
        // ------- mini-scatter -------
        int e = (blockIdx.x - 5 * NB2) * 256 + t;
        if (e < E) {
            int dst = EI[E + e];
            int pos = atomicAdd(&cursor[dst], 1);
            SE[pos] = make_int2(EI[e], e);
        }
        return;
    }

    // ------- gemm slice (128 rows) -------
    const int bid = blockIdx.x;
    const int m = bid / NB2;
    const int bx = bid - m * NB2;
    const int widx = (m < 4) ? m : 6;
    const int lane = t & 63;
    const int w = t >> 6;
    const int row0 = bx * 128 + w * 32;
    const int lrow = lane & 15;
    const int kb = (lane >> 4) * 8;
    const int rq = (lane >> 4) * 4;

    const unsigned short* gsrc = Wt + (size_t)widx * 16384;
    ushort8 stg[8];
#pragma unroll
    for (int it = 0; it < 8; ++it)
        stg[it] = *(const ushort8*)(gsrc + (t + it * 256) * 8);

    bf16x8 af0[4], af1[4];
    {
        int a0 = row0 + lrow;      if (a0 > N - 1) a0 = N - 1;
        int a1 = row0 + 16 + lrow; if (a1 > N - 1) a1 = N - 1;
        const unsigned short* x0 = XB + (size_t)a0 * D + kb;
        const unsigned short* x1 = XB + (size_t)a1 * D + kb;
#pragma unroll
        for (int kf = 0; kf < 4; ++kf) {
            af0[kf] = *(const bf16x8*)(x0 + kf * 32);
            af1[kf] = *(const bf16x8*)(x1 + kf * 32);
        }
    }

#pragma unroll
    for (int it = 0; it < 8; ++it)
        *(ushort8*)(&sw[(t + it * 256) * 8]) = stg[it];
    __syncthreads();

    const float* bias = (m == 0) ? bq : (m == 1) ? bk : (m == 2) ? bv
                      : (m == 3) ? bs : bqE;
    f32x4 acc0[8], acc1[8];
#pragma unroll
    for (int nf = 0; nf < 8; ++nf) {
        acc0[nf] = (f32x4){0.f, 0.f, 0.f, 0.f};
        acc1[nf] = (f32x4){0.f, 0.f, 0.f, 0.f};
    }
#pragma unroll
    for (int nf = 0; nf < 8; ++nf) {
        const int col = nf * 16 + lrow;
#pragma unroll
        for (int kf = 0; kf < 4; ++kf) {
            bf16x8 bfr = ldsB(sw, col, kf * 32 + kb);
            acc0[nf] = __builtin_amdgcn_mfma_f32_16x16x32_bf16(af0[kf], bfr, acc0[nf], 0, 0, 0);
            acc1[nf] = __builtin_amdgcn_mfma_f32_16x16x32_bf16(af1[kf], bfr, acc1[nf], 0, 0, 0);
        }
    }
#pragma unroll
    for (int rb = 0; rb < 2; ++rb) {
#pragma unroll
        for (int nf = 0; nf < 8; ++nf) {
            const int col = nf * 16 + lrow;
            const float bb = bias[col];
#pragma unroll
            for (int i = 0; i < 4; ++i) {
                int r = row0 + rb * 16 + rq + i;
                if (r < N) {
                    float v = ((rb == 0) ? acc0[nf][i] : acc1[nf][i]) + bb;
                    if (m == 0)      QA[(size_t)r * 256 + col]       = f2bf(v);
                    else if (m == 1) KV[(size_t)r * 256 + col]       = f2bf(v);
                    else if (m == 2) KV[(size_t)r * 256 + 128 + col] = f2bf(v);
                    else if (m == 3) S[(size_t)r * D + col]          = v;
                    else             QA[(size_t)r * 256 + 128 + col] = f2bf(v);
                }
            }
        }
    }
}

// ---------------------------------------------------------------------------
// gather: 1 wave per node; 4 edge groups x 16 lanes (lane owns 8 dims),
// 2 edges per group per iteration. edge_attr read DIRECTLY (fp32, via eid).
// ---------------------------------------------------------------------------
__global__ __launch_bounds__(256) void gather_pass(
    const int* __restrict__ rowptr, const int2* __restrict__ SE,
    const float* __restrict__ EA,
    const unsigned short* __restrict__ QA, const unsigned short* __restrict__ KV,
    float* __restrict__ SB, unsigned short* __restrict__ SAS, int N)
{
    const int lane = threadIdx.x & 63;
    const int wid = threadIdx.x >> 6;
    const int n = blockIdx.x * 4 + wid;
    if (n >= N) return;
    const int g = lane & 15;        // dim slice: d = g*8..+8 (head g>>2)
    const int grp = lane >> 4;      // edge group 0..3
    const int eoff = (g & 3) * 8;   // this lane's EA slice (floats)

    float q8[8], qe8[8];
    {
        const unsigned short* qa = QA + (size_t)n * 256 + g * 8;
        bf16x8 qb  = *(const bf16x8*)(qa);
        bf16x8 qeb = *(const bf16x8*)(qa + 128);
#pragma unroll
        for (int j = 0; j < 8; ++j) {
            q8[j]  = bf2f((unsigned short)qb[j]);
            qe8[j] = bf2f((unsigned short)qeb[j]);
        }
    }

    float acc[8], sa[8], den = 0.f;
#pragma unroll
    for (int j = 0; j < 8; ++j) { acc[j] = 0.f; sa[j] = 0.f; }

    const int i0 = rowptr[n], i1 = rowptr[n + 1];

    int iA = i0 + grp, iB = iA + 4;
    int2 seA = (iA < i1) ? SE[iA] : make_int2(-1, 0);
    int2 seB = (iB < i1) ? SE[iB] : make_int2(-1, 0);

    for (int b = i0; b < i1; b += 8) {
        const int iA2 = iA + 8, iB2 = iB + 8;
        const int2 seA2 = (iA2 < i1) ? SE[iA2] : make_int2(-1, 0);
        const int2 seB2 = (iB2 < i1) ? SE[iB2] : make_int2(-1, 0);

        bf16x8 kA = {0,0,0,0,0,0,0,0}, vA = kA;
        bf16x8 kB = kA, vB = kA;
        float4 eA0 = {0,0,0,0}, eA1 = eA0, eB0 = eA0, eB1 = eA0;
        if (seA.x >= 0) {
            const unsigned short* kv = KV + (size_t)seA.x * 256 + g * 8;
            kA = *(const bf16x8*)(kv);
            vA = *(const bf16x8*)(kv + 128);
            const float* ear = EA + (size_t)seA.y * EDIM + eoff;
            eA0 = *(const float4*)(ear);
            eA1 = *(const float4*)(ear + 4);
        }
        if (seB.x >= 0) {
            const unsigned short* kv = KV + (size_t)seB.x * 256 + g * 8;
            kB = *(const bf16x8*)(kv);
            vB = *(const bf16x8*)(kv + 128);
            const float* ear = EA + (size_t)seB.y * EDIM + eoff;
            eB0 = *(const float4*)(ear);
            eB1 = *(const float4*)(ear + 4);
        }

        {
            float ef[8] = {eA0.x, eA0.y, eA0.z, eA0.w, eA1.x, eA1.y, eA1.z, eA1.w};
            float p = 0.f;
#pragma unroll
            for (int j = 0; j < 8; ++j)
                p = fmaf(q8[j], bf2f((unsigned short)kA[j]),
                         fmaf(ef[j], qe8[j], p));
            p = quad_add(p);
            const float ex = (seA.x >= 0) ? __expf(p * 0.17677669529663689f) : 0.f;
            den += ex;
#pragma unroll
            for (int j = 0; j < 8; ++j) {
                acc[j] = fmaf(ex, bf2f((unsigned short)vA[j]), acc[j]);
                sa[j]  = fmaf(ex, ef[j], sa[j]);
            }
        }
        {
            float ef[8] = {eB0.x, eB0.y, eB0.z, eB0.w, eB1.x, eB1.y, eB1.z, eB1.w};
            float p = 0.f;
#pragma unroll
            for (int j = 0; j < 8; ++j)
                p = fmaf(q8[j], bf2f((unsigned short)kB[j]),
                         fmaf(ef[j], qe8[j], p));
            p = quad_add(p);
            const float ex = (seB.x >= 0) ? __expf(p * 0.17677669529663689f) : 0.f;
            den += ex;
#pragma unroll
            for (int j = 0; j < 8; ++j) {
                acc[j] = fmaf(ex, bf2f((unsigned short)vB[j]), acc[j]);
                sa[j]  = fmaf(ex, ef[j], sa[j]);
            }
        }
        iA = iA2; iB = iB2; seA = seA2; seB = seB2;
    }

#pragma unroll
    for (int off = 16; off <= 32; off <<= 1) {
        den += __shfl_xor(den, off, 64);
#pragma unroll
        for (int j = 0; j < 8; ++j) {
            acc[j] += __shfl_xor(acc[j], off, 64);
            sa[j]  += __shfl_xor(sa[j],  off, 64);
        }
    }

    if (grp == 0) {
        const float rden = 1.f / (den + 1e-16f);
        float* so = SB + (size_t)n * D + g * 8;
        unsigned short* po = SAS + (size_t)n * D + g * 8;
#pragma unroll
        for (int j = 0; j < 8; ++j) {
            so[j] = fmaf(acc[j], rden, so[j]);    // + skip (in place)
            po[j] = f2bf(sa[j] * rden);
        }
    }
}

// ---------------------------------------------------------------------------
// fused_mlp: OUT = preout + SAS @ WtCorr; H1 = gelu(OUT@W1+b1);
//            FINAL = OUT + gelu(H1@W2+b2).
// ---------------------------------------------------------------------------
__global__ __launch_bounds__(256) void fused_mlp(
    const float* __restrict__ SB, const unsigned short* __restrict__ SAS,
    const unsigned short* __restrict__ WtC, const unsigned short* __restrict__ Wt1,
    const unsigned short* __restrict__ Wt2,
    const float* __restrict__ b1, const float* __restrict__ b2,
    float* __restrict__ FINAL, int N)
{
    __shared__ unsigned short sw[16384];
    __shared__ unsigned short bounce[64 * 136];
    const int t = threadIdx.x;
    const int lane = t & 63;
    const int w = t >> 6;
    const int row0 = blockIdx.x * 64 + w * 16;
    const int lrow = lane & 15;
    const int kb = (lane >> 4) * 8;
    const int rq = (lane >> 4) * 4;

    ushort8 stg[8];
#pragma unroll
    for (int it = 0; it < 8; ++it)
        stg[it] = *(const ushort8*)(WtC + (t + it * 256) * 8);

    bf16x8 af[4];
    {
        int ar = row0 + lrow; if (ar > N - 1) ar = N - 1;
        const unsigned short* xr = SAS + (size_t)ar * D + kb;
#pragma unroll
        for (int kf = 0; kf < 4; ++kf) af[kf] = *(const bf16x8*)(xr + kf * 32);
    }
    f32x4 out[8];
#pragma unroll
    for (int nf = 0; nf < 8; ++nf) {
        const int col = nf * 16 + lrow;
#pragma unroll
        for (int i = 0; i < 4; ++i) {
            int r = row0 + rq + i;
            out[nf][i] = (r < N) ? SB[(size_t)r * D + col] : 0.f;
        }
    }
#pragma unroll
    for (int it = 0; it < 8; ++it)
        *(ushort8*)(&sw[(t + it * 256) * 8]) = stg[it];
    __syncthreads();

    // GEMM1
#pragma unroll
    for (int nf = 0; nf < 8; ++nf) {
        const int col = nf * 16 + lrow;
#pragma unroll
        for (int kf = 0; kf < 4; ++kf)
            out[nf] = __builtin_amdgcn_mfma_f32_16x16x32_bf16(
                af[kf], ldsB(sw, col, kf * 32 + kb), out[nf], 0, 0, 0);
    }
    __syncthreads();

    // bounce OUT + stage Wt1
#pragma unroll
    for (int it = 0; it < 8; ++it)
        stg[it] = *(const ushort8*)(Wt1 + (t + it * 256) * 8);
#pragma unroll
    for (int nf = 0; nf < 8; ++nf) {
        const int col = nf * 16 + lrow;
#pragma unroll
        for (int i = 0; i < 4; ++i)
            bounce[(w * 16 + rq + i) * 136 + col] = f2bf(out[nf][i]);
    }
#pragma unroll
    for (int it = 0; it < 8; ++it)
        *(ushort8*)(&sw[(t + it * 256) * 8]) = stg[it];
    __syncthreads();

    // GEMM2
    bf16x8 af2[4];
#pragma unroll
    for (int kf = 0; kf < 4; ++kf)
        af2[kf] = *(const bf16x8*)(&bounce[(w * 16 + lrow) * 136 + kb + kf * 32]);
    f32x4 acc2[8];
#pragma unroll
    for (int nf = 0; nf < 8; ++nf) acc2[nf] = (f32x4){0.f, 0.f, 0.f, 0.f};
#pragma unroll
    for (int nf = 0; nf < 8; ++nf) {
        const int col = nf * 16 + lrow;
#pragma unroll
        for (int kf = 0; kf < 4; ++kf)
            acc2[nf] = __builtin_amdgcn_mfma_f32_16x16x32_bf16(
                af2[kf], ldsB(sw, col, kf * 32 + kb), acc2[nf], 0, 0, 0);
    }
    __syncthreads();

    // bounce H1 + stage Wt2
#pragma unroll
    for (int it = 0; it < 8; ++it)
        stg[it] = *(const ushort8*)(Wt2 + (t + it * 256) * 8);
#pragma unroll
    for (int nf = 0; nf < 8; ++nf) {
        const int col = nf * 16 + lrow;
        const float bb = b1[col];
#pragma unroll
        for (int i = 0; i < 4; ++i)
            bounce[(w * 16 + rq + i) * 136 + col] = f2bf(gelu_fast(acc2[nf][i] + bb));
    }
#pragma unroll
    for (int it = 0; it < 8; ++it)
        *(ushort8*)(&sw[(t + it * 256) * 8]) = stg[it];
    __syncthreads();

    // GEMM3 + epilogue
    bf16x8 af3[4];
#pragma unroll
    for (int kf = 0; kf < 4; ++kf)
        af3[kf] = *(const bf16x8*)(&bounce[(w * 16 + lrow) * 136 + kb + kf * 32]);
    f32x4 acc3[8];
#pragma unroll
    for (int nf = 0; nf < 8; ++nf) acc3[nf] = (f32x4){0.f, 0.f, 0.f, 0.f};
#pragma unroll
    for (int nf = 0; nf < 8; ++nf) {
        const int col = nf * 16 + lrow;
#pragma unroll
        for (int kf = 0; kf < 4; ++kf)
            acc3[nf] = __builtin_amdgcn_mfma_f32_16x16x32_bf16(
                af3[kf], ldsB(sw, col, kf * 32 + kb), acc3[nf], 0, 0, 0);
    }
#pragma unroll
    for (int nf = 0; nf < 8; ++nf) {
        const int col = nf * 16 + lrow;
        const float bb = b2[col];
#pragma unroll
        for (int i = 0; i < 4; ++i) {
            int r = row0 + rq + i;
            if (r < N)
                FINAL[(size_t)r * D + col] = out[nf][i] + gelu_fast(acc3[nf][i] + bb);
        }
    }
}

// ---------------------------------------------------------------------------
extern "C" void kernel_launch(void* const* d_in, const int* in_sizes, int n_in,
                              void* d_out, int out_size, void* d_ws, size_t ws_size,
                              hipStream_t stream)
{
    const float* x   = (const float*)d_in[0];
    const int*   EI  = (const int*)  d_in[1];
    const float* EA  = (const float*)d_in[2];
    const float* Wq  = (const float*)d_in[3];
    const float* bq  = (const float*)d_in[4];
    const float* Wk  = (const float*)d_in[5];
    const float* bk  = (const float*)d_in[6];
    const float* Wv  = (const float*)d_in[7];
    const float* bv  = (const float*)d_in[8];
    const float* We  = (const float*)d_in[9];
    const float* Wsk = (const float*)d_in[10];
    const float* bsk = (const float*)d_in[11];
    const float* W1  = (const float*)d_in[12];
    const float* b1  = (const float*)d_in[13];
    const float* W2  = (const float*)d_in[14];
    const float* b2  = (const float*)d_in[15];

    const int N = in_sizes[0] / D;
    const int E = in_sizes[1] / 2;

    char* p = (char*)d_ws;
    auto alloc = [&](size_t bytes) -> void* {
        void* r = (void*)p;
        p += (bytes + 255) & ~(size_t)255;
        return r;
    };
    float*          Sb     = (float*)         alloc((size_t)N * D * 4);   // skip -> preout
    unsigned short* QAb    = (unsigned short*)alloc((size_t)N * 256 * 2); // [Q|QE]
    unsigned short* KVb    = (unsigned short*)alloc((size_t)N * 256 * 2); // [K|V]
    unsigned short* SASb   = (unsigned short*)alloc((size_t)N * D * 2);
    unsigned short* XBb    = (unsigned short*)alloc((size_t)N * D * 2);   // bf16 x
    int2*           SEb    = (int2*)          alloc((size_t)E * 8);
    unsigned short* Wt     = (unsigned short*)alloc((size_t)8 * 16384 * 2);
    float*          bqEb   = (float*)         alloc((size_t)128 * 4);
    int*            deg    = (int*)           alloc((size_t)N * 4);
    int*            rowptr = (int*)           alloc((size_t)(N + 1) * 4);
    int*            cursor = (int*)           alloc((size_t)(N + 1) * 4);
    int*            psums  = (int*)           alloc((size_t)1024 * 4);

    hipMemsetAsync(deg, 0, (size_t)N * sizeof(int), stream);

    const long xtot = (long)N * D;
    const int NB  = (N + 63) / 64;
    const int NB2 = (N + 127) / 128;
    const int EB  = (E + 255) / 256;
    const int XB_ = (int)((xtot + 2047) / 2048);
    const int SB_ = (N + 1023) / 1024;

    prep_kernel<<<513 + EB + XB_, 256, 0, stream>>>(
        Wq, Wk, Wv, Wsk, W1, W2, We, bq, Wt, bqEb, EI, deg, E, EB, x, XBb, xtot);

    scanA<<<SB_, 1024, 0, stream>>>(deg, rowptr, psums, N);
    scanB<<<1, 1024, 0, stream>>>(psums, SB_);
    scanC<<<(N + 255) / 256, 256, 0, stream>>>(rowptr, cursor, psums, N);

    mega_gemm_scatter<<<5 * NB2 + EB, 256, 0, stream>>>(
        XBb, Wt, bq, bk, bv, bsk, bqEb, QAb, KVb, Sb, N, NB2,
        EI, cursor, SEb, E);

    gather_pass<<<(N + 3) / 4, 256, 0, stream>>>(
        rowptr, SEb, EA, QAb, KVb, Sb, SASb, N);

    fused_mlp<<<NB, 256, 0, stream>>>(Sb, SASb,
                                      Wt + (size_t)7 * 16384,
                                      Wt + (size_t)4 * 16384,
                                      Wt + (size_t)5 * 16384,
                                      b1, b2, (float*)d_out, N);
}

// Round 10
// 265.670 us; speedup vs baseline: 1.0529x; 1.0529x over previous
//
#include <hip/hip_runtime.h>
#include <math.h>

// ---------------------------------------------------------------------------
// GraphTransformerBlock: TransformerConv (4 heads x 32) + residual MLP.
// Round 10:
//  - GEMM bf16 outputs bounced through LDS (re-using the weight tile buffer)
//    -> full-line coalesced ushort8 stores (kills ~48MB partial-line RMW
//    write amplification that capped mega at ~1.4 TB/s effective).
//  - scatter split back into its own kernel (attribution + occupancy).
// ---------------------------------------------------------------------------

#define D 128
#define EDIM 32

using bf16x8 = __attribute__((ext_vector_type(8))) short;
using f32x4  = __attribute__((ext_vector_type(4))) float;
using ushort8 = __attribute__((ext_vector_type(8))) unsigned short;

__device__ inline unsigned short f2bf(float f) {
    unsigned int u = __float_as_uint(f);
    u += 0x7FFFu + ((u >> 16) & 1u);          // round-to-nearest-even
    return (unsigned short)(u >> 16);
}
__device__ inline float bf2f(unsigned short h) {
    return __uint_as_float(((unsigned int)h) << 16);
}
__device__ inline float gelu_fast(float x) {
    float x3 = x * x * x;
    float u = 0.7978845608028654f * (x + 0.044715f * x3);
    float t = 1.f - 2.f / (__expf(2.f * u) + 1.f);   // tanh(u)
    return 0.5f * x * (1.f + t);
}
// sum over aligned 4-lane quad via DPP quad_perm (all 4 lanes get the sum)
__device__ inline float quad_add(float x) {
    int a = __builtin_amdgcn_update_dpp(0, __float_as_int(x), 0xB1, 0xF, 0xF, true);
    x += __int_as_float(a);
    a = __builtin_amdgcn_update_dpp(0, __float_as_int(x), 0x4E, 0xF, 0xF, true);
    x += __int_as_float(a);
    return x;
}

// swizzled B-frag read: element (col, kk0..kk0+7) of the staged weight tile
__device__ inline bf16x8 ldsB(const unsigned short* sw, int col, int kk0) {
    return *(const bf16x8*)(sw + col * 128 + (kk0 ^ ((col & 7) << 3)));
}

// ---------------------------------------------------------------------------
// prep: blocks 0..511 -> 8 pre-swizzled bf16 weight tables
//   Wt[m][col*128 + (kk ^ ((col&7)<<3))] = W_m[kk][col]
//   m: 0=Wq 1=Wk 2=Wv 3=Wskip 4=W1 5=W2 6=WqE (inline dot) 7=WtCorr
// block 512: bqE.  blocks 513..513+HB-1: hist. blocks 513+HB..: x -> bf16.
// ---------------------------------------------------------------------------
__global__ __launch_bounds__(256) void prep_kernel(
    const float* __restrict__ Wq, const float* __restrict__ Wk,
    const float* __restrict__ Wv, const float* __restrict__ Wsk,
    const float* __restrict__ W1, const float* __restrict__ W2,
    const float* __restrict__ We, const float* __restrict__ bq,
    unsigned short* __restrict__ Wt, float* __restrict__ bqE,
    const int* __restrict__ EI, int* __restrict__ deg, int E, int HB,
    const float* __restrict__ x, unsigned short* __restrict__ XB, long xtot)
{
    if ((int)blockIdx.x >= 513 + HB) {    // x -> bf16 tail
        long i8 = ((long)(blockIdx.x - 513 - HB) * 256 + threadIdx.x) * 8;
        if (i8 + 8 <= xtot) {
            float4 a = *(const float4*)(x + i8);
            float4 b = *(const float4*)(x + i8 + 4);
            ushort8 u;
            u[0] = f2bf(a.x); u[1] = f2bf(a.y); u[2] = f2bf(a.z); u[3] = f2bf(a.w);
            u[4] = f2bf(b.x); u[5] = f2bf(b.y); u[6] = f2bf(b.z); u[7] = f2bf(b.w);
            *(ushort8*)(XB + i8) = u;
        }
        return;
    }
    if (blockIdx.x >= 513) {              // hist
        int e = (blockIdx.x - 513) * 256 + threadIdx.x;
        if (e < E) atomicAdd(&deg[EI[E + e]], 1);
        return;
    }
    int t = blockIdx.x * 256 + threadIdx.x;
    int m = t >> 14;
    int r = t & 16383;
    if (m >= 8) {                         // bqE block
        if (r < 128) {
            const int hb = r & 96, k = r & 31;
            const float* wek = We + (size_t)k * D + hb;
            float s = 0.f;
#pragma unroll 8
            for (int c = 0; c < 32; ++c) s = fmaf(bq[hb + c], wek[c], s);
            bqE[r] = s;
        }
        return;
    }
    int col = r & 127, kk = r >> 7;
    float v;
    if (m < 6) {
        const float* W = (m == 0) ? Wq : (m == 1) ? Wk : (m == 2) ? Wv
                       : (m == 3) ? Wsk : (m == 4) ? W1 : W2;
        v = W[(size_t)kk * D + col];
    } else if (m == 6) {
        const int hb = col & 96;
        const float* wqr = Wq + (size_t)kk * D + hb;
        const float* wer = We + (size_t)(col & 31) * D + hb;
        float s = 0.f;
#pragma unroll 8
        for (int c = 0; c < 32; ++c) s = fmaf(wqr[c], wer[c], s);
        v = s;
    } else {
        v = ((kk >> 5) == (col >> 5)) ? We[(size_t)(kk & 31) * D + col] : 0.f;
    }
    Wt[(size_t)m * 16384 + (size_t)col * 128 + (kk ^ ((col & 7) << 3))] = f2bf(v);
}

// ---------------------------------------------------------------------------
// hierarchical scan
// ---------------------------------------------------------------------------
__global__ __launch_bounds__(1024) void scanA(
    const int* __restrict__ deg, int* __restrict__ rowptr,
    int* __restrict__ psums, int N)
{
    __shared__ int tmp[1024];
    const int t = threadIdx.x;
    const int i = blockIdx.x * 1024 + t;
    int v = (i < N) ? deg[i] : 0;
    tmp[t] = v;
    __syncthreads();
    for (int off = 1; off < 1024; off <<= 1) {
        int add = (t >= off) ? tmp[t - off] : 0;
        __syncthreads();
        tmp[t] += add;
        __syncthreads();
    }
    if (i < N) rowptr[i + 1] = tmp[t];
    if (t == 1023) psums[blockIdx.x] = tmp[1023];
}

__global__ __launch_bounds__(1024) void scanB(int* __restrict__ psums, int nb)
{
    __shared__ int tmp[1024];
    const int t = threadIdx.x;
    int v = (t < nb) ? psums[t] : 0;
    tmp[t] = v;
    __syncthreads();
    for (int off = 1; off < 1024; off <<= 1) {
        int add = (t >= off) ? tmp[t - off] : 0;
        __syncthreads();
        tmp[t] += add;
        __syncthreads();
    }
    if (t < nb) psums[t] = tmp[t] - v;   // exclusive
}

__global__ __launch_bounds__(256) void scanC(
    int* __restrict__ rowptr, int* __restrict__ cursor,
    const int* __restrict__ psums, int N)
{
    int i = blockIdx.x * 256 + threadIdx.x;
    if (i == 0) { rowptr[0] = 0; cursor[0] = 0; }
    if (i < N) {
        int val = rowptr[i + 1] + psums[i >> 10];
        rowptr[i + 1] = val;
        if (i + 1 < N) cursor[i + 1] = val;
    }
}

// ---------------------------------------------------------------------------
// scatter: (src,eid) int2 per edge into CSR position. No LDS -> full occupancy.
// ---------------------------------------------------------------------------
__global__ __launch_bounds__(256) void scatter_kernel(
    const int* __restrict__ EI, int* __restrict__ cursor,
    int2* __restrict__ SE, int E)
{
    int e = blockIdx.x * 256 + threadIdx.x;
    if (e < E) {
        int dst = EI[E + e];
        int pos = atomicAdd(&cursor[dst], 1);
        SE[pos] = make_int2(EI[e], e);
    }
}

// ---------------------------------------------------------------------------
// gemm5: blockIdx.x = m*NB2 + bx, m=0..4 (Q,K,V,skip,QE). 128-row tiles.
// bf16 outputs (m!=3) are transposed through LDS (re-using sw) so global
// stores are full-line ushort8; skip (m==3) stores f32 directly.
// ---------------------------------------------------------------------------
__global__ __launch_bounds__(256) void gemm5(
    const unsigned short* __restrict__ XB, const unsigned short* __restrict__ Wt,
    const float* __restrict__ bq, const float* __restrict__ bk,
    const float* __restrict__ bv, const float* __restrict__ bs,
    const float* __restrict__ bqE,
    unsigned short* __restrict__ QA, unsigned short* __restrict__ KV,
    float* __restrict__ S, int N, int NB2)
{
    __shared__ unsigned short sw[16384];
    const int t = threadIdx.x;
    const int bid = blockIdx.x;
    const int m = bid / NB2;
    const int bx = bid - m * NB2;
    const int widx = (m < 4) ? m : 6;
    const int lane = t & 63;
    const int w = t >> 6;
    const int row0 = bx * 128 + w * 32;
    const int lrow = lane & 15;
    const int kb = (lane >> 4) * 8;
    const int rq = (lane >> 4) * 4;

    const unsigned short* gsrc = Wt + (size_t)widx * 16384;
    ushort8 stg[8];
#pragma unroll
    for (int it = 0; it < 8; ++it)
        stg[it] = *(const ushort8*)(gsrc + (t + it * 256) * 8);

    bf16x8 af0[4], af1[4];
    {
        int a0 = row0 + lrow;      if (a0 > N - 1) a0 = N - 1;
        int a1 = row0 + 16 + lrow; if (a1 > N - 1) a1 = N - 1;
        const unsigned short* x0 = XB + (size_t)a0 * D + kb;
        const unsigned short* x1 = XB + (size_t)a1 * D + kb;
#pragma unroll
        for (int kf = 0; kf < 4; ++kf) {
            af0[kf] = *(const bf16x8*)(x0 + kf * 32);
            af1[kf] = *(const bf16x8*)(x1 + kf * 32);
        }
    }

#pragma unroll
    for (int it = 0; it < 8; ++it)
        *(ushort8*)(&sw[(t + it * 256) * 8]) = stg[it];
    __syncthreads();

    const float* bias = (m == 0) ? bq : (m == 1) ? bk : (m == 2) ? bv
                      : (m == 3) ? bs : bqE;
    f32x4 acc0[8], acc1[8];
#pragma unroll
    for (int nf = 0; nf < 8; ++nf) {
        acc0[nf] = (f32x4){0.f, 0.f, 0.f, 0.f};
        acc1[nf] = (f32x4){0.f, 0.f, 0.f, 0.f};
    }
#pragma unroll
    for (int nf = 0; nf < 8; ++nf) {
        const int col = nf * 16 + lrow;
#pragma unroll
        for (int kf = 0; kf < 4; ++kf) {
            bf16x8 bfr = ldsB(sw, col, kf * 32 + kb);
            acc0[nf] = __builtin_amdgcn_mfma_f32_16x16x32_bf16(af0[kf], bfr, acc0[nf], 0, 0, 0);
            acc1[nf] = __builtin_amdgcn_mfma_f32_16x16x32_bf16(af1[kf], bfr, acc1[nf], 0, 0, 0);
        }
    }

    if (m == 3) {
        // f32 skip: direct stores (64B-contiguous per (nf,row) segment)
#pragma unroll
        for (int rb = 0; rb < 2; ++rb) {
#pragma unroll
            for (int nf = 0; nf < 8; ++nf) {
                const int col = nf * 16 + lrow;
                const float bb = bias[col];
#pragma unroll
                for (int i = 0; i < 4; ++i) {
                    int r = row0 + rb * 16 + rq + i;
                    if (r < N)
                        S[(size_t)r * D + col] = ((rb == 0) ? acc0[nf][i] : acc1[nf][i]) + bb;
                }
            }
        }
        return;
    }

    // bf16 outputs: bounce through sw (barrier: all MFMA sw-reads are done)
    __syncthreads();
#pragma unroll
    for (int rb = 0; rb < 2; ++rb) {
#pragma unroll
        for (int nf = 0; nf < 8; ++nf) {
            const int col = nf * 16 + lrow;
            const float bb = bias[col];
#pragma unroll
            for (int i = 0; i < 4; ++i)
                sw[(w * 32 + rb * 16 + rq + i) * 128 + col] =
                    f2bf(((rb == 0) ? acc0[nf][i] : acc1[nf][i]) + bb);
        }
    }
    // per-wave patch readback (no cross-wave dependency -> no extra barrier)
    unsigned short* gout = (m == 0) ? QA : (m == 1) ? KV
                         : (m == 2) ? KV + 128 : QA + 128;
#pragma unroll
    for (int it = 0; it < 8; ++it) {
        const int gidx = it * 64 + lane;
        const int row_l = gidx >> 4;          // 0..31
        const int chk = gidx & 15;            // 16B chunk within row
        const int r = row0 + row_l;
        ushort8 vv = *(const ushort8*)(&sw[(w * 32 + row_l) * 128 + chk * 8]);
        if (r < N) *(ushort8*)(gout + (size_t)r * 256 + chk * 8) = vv;
    }
}

// ---------------------------------------------------------------------------
// gather: 1 wave per node; 4 edge groups x 16 lanes (lane owns 8 dims),
// 2 edges per group per iteration. edge_attr read DIRECTLY (fp32, via eid).
// ---------------------------------------------------------------------------
__global__ __launch_bounds__(256) void gather_pass(
    const int* __restrict__ rowptr, const int2* __restrict__ SE,
    const float* __restrict__ EA,
    const unsigned short* __restrict__ QA, const unsigned short* __restrict__ KV,
    float* __restrict__ SB, unsigned short* __restrict__ SAS, int N)
{
    const int lane = threadIdx.x & 63;
    const int wid = threadIdx.x >> 6;
    const int n = blockIdx.x * 4 + wid;
    if (n >= N) return;
    const int g = lane & 15;        // dim slice: d = g*8..+8 (head g>>2)
    const int grp = lane >> 4;      // edge group 0..3
    const int eoff = (g & 3) * 8;   // this lane's EA slice (floats)

    float q8[8], qe8[8];
    {
        const unsigned short* qa = QA + (size_t)n * 256 + g * 8;
        bf16x8 qb  = *(const bf16x8*)(qa);
        bf16x8 qeb = *(const bf16x8*)(qa + 128);
#pragma unroll
        for (int j = 0; j < 8; ++j) {
            q8[j]  = bf2f((unsigned short)qb[j]);
            qe8[j] = bf2f((unsigned short)qeb[j]);
        }
    }

    float acc[8], sa[8], den = 0.f;
#pragma unroll
    for (int j = 0; j < 8; ++j) { acc[j] = 0.f; sa[j] = 0.f; }

    const int i0 = rowptr[n], i1 = rowptr[n + 1];

    int iA = i0 + grp, iB = iA + 4;
    int2 seA = (iA < i1) ? SE[iA] : make_int2(-1, 0);
    int2 seB = (iB < i1) ? SE[iB] : make_int2(-1, 0);

    for (int b = i0; b < i1; b += 8) {
        const int iA2 = iA + 8, iB2 = iB + 8;
        const int2 seA2 = (iA2 < i1) ? SE[iA2] : make_int2(-1, 0);
        const int2 seB2 = (iB2 < i1) ? SE[iB2] : make_int2(-1, 0);

        bf16x8 kA = {0,0,0,0,0,0,0,0}, vA = kA;
        bf16x8 kB = kA, vB = kA;
        float4 eA0 = {0,0,0,0}, eA1 = eA0, eB0 = eA0, eB1 = eA0;
        if (seA.x >= 0) {
            const unsigned short* kv = KV + (size_t)seA.x * 256 + g * 8;
            kA = *(const bf16x8*)(kv);
            vA = *(const bf16x8*)(kv + 128);
            const float* ear = EA + (size_t)seA.y * EDIM + eoff;
            eA0 = *(const float4*)(ear);
            eA1 = *(const float4*)(ear + 4);
        }
        if (seB.x >= 0) {
            const unsigned short* kv = KV + (size_t)seB.x * 256 + g * 8;
            kB = *(const bf16x8*)(kv);
            vB = *(const bf16x8*)(kv + 128);
            const float* ear = EA + (size_t)seB.y * EDIM + eoff;
            eB0 = *(const float4*)(ear);
            eB1 = *(const float4*)(ear + 4);
        }

        {
            float ef[8] = {eA0.x, eA0.y, eA0.z, eA0.w, eA1.x, eA1.y, eA1.z, eA1.w};
            float p = 0.f;
#pragma unroll
            for (int j = 0; j < 8; ++j)
                p = fmaf(q8[j], bf2f((unsigned short)kA[j]),
                         fmaf(ef[j], qe8[j], p));
            p = quad_add(p);
            const float ex = (seA.x >= 0) ? __expf(p * 0.17677669529663689f) : 0.f;
            den += ex;
#pragma unroll
            for (int j = 0; j < 8; ++j) {
                acc[j] = fmaf(ex, bf2f((unsigned short)vA[j]), acc[j]);
                sa[j]  = fmaf(ex, ef[j], sa[j]);
            }
        }
        {
            float ef[8] = {eB0.x, eB0.y, eB0.z, eB0.w, eB1.x, eB1.y, eB1.z, eB1.w};
            float p = 0.f;
#pragma unroll
            for (int j = 0; j < 8; ++j)
                p = fmaf(q8[j], bf2f((unsigned short)kB[j]),
                         fmaf(ef[j], qe8[j], p));
            p = quad_add(p);
            const float ex = (seB.x >= 0) ? __expf(p * 0.17677669529663689f) : 0.f;
            den += ex;
#pragma unroll
            for (int j = 0; j < 8; ++j) {
                acc[j] = fmaf(ex, bf2f((unsigned short)vB[j]), acc[j]);
                sa[j]  = fmaf(ex, ef[j], sa[j]);
            }
        }
        iA = iA2; iB = iB2; seA = seA2; seB = seB2;
    }

#pragma unroll
    for (int off = 16; off <= 32; off <<= 1) {
        den += __shfl_xor(den, off, 64);
#pragma unroll
        for (int j = 0; j < 8; ++j) {
            acc[j] += __shfl_xor(acc[j], off, 64);
            sa[j]  += __shfl_xor(sa[j],  off, 64);
        }
    }

    if (grp == 0) {
        const float rden = 1.f / (den + 1e-16f);
        float* so = SB + (size_t)n * D + g * 8;
        unsigned short* po = SAS + (size_t)n * D + g * 8;
#pragma unroll
        for (int j = 0; j < 8; ++j) {
            so[j] = fmaf(acc[j], rden, so[j]);    // + skip (in place)
            po[j] = f2bf(sa[j] * rden);
        }
    }
}

// ---------------------------------------------------------------------------
// fused_mlp: OUT = preout + SAS @ WtCorr; H1 = gelu(OUT@W1+b1);
//            FINAL = OUT + gelu(H1@W2+b2).
// ---------------------------------------------------------------------------
__global__ __launch_bounds__(256) void fused_mlp(
    const float* __restrict__ SB, const unsigned short* __restrict__ SAS,
    const unsigned short* __restrict__ WtC, const unsigned short* __restrict__ Wt1,
    const unsigned short* __restrict__ Wt2,
    const float* __restrict__ b1, const float* __restrict__ b2,
    float* __restrict__ FINAL, int N)
{
    __shared__ unsigned short sw[16384];
    __shared__ unsigned short bounce[64 * 136];
    const int t = threadIdx.x;
    const int lane = t & 63;
    const int w = t >> 6;
    const int row0 = blockIdx.x * 64 + w * 16;
    const int lrow = lane & 15;
    const int kb = (lane >> 4) * 8;
    const int rq = (lane >> 4) * 4;

    ushort8 stg[8];
#pragma unroll
    for (int it = 0; it < 8; ++it)
        stg[it] = *(const ushort8*)(WtC + (t + it * 256) * 8);

    bf16x8 af[4];
    {
        int ar = row0 + lrow; if (ar > N - 1) ar = N - 1;
        const unsigned short* xr = SAS + (size_t)ar * D + kb;
#pragma unroll
        for (int kf = 0; kf < 4; ++kf) af[kf] = *(const bf16x8*)(xr + kf * 32);
    }
    f32x4 out[8];
#pragma unroll
    for (int nf = 0; nf < 8; ++nf) {
        const int col = nf * 16 + lrow;
#pragma unroll
        for (int i = 0; i < 4; ++i) {
            int r = row0 + rq + i;
            out[nf][i] = (r < N) ? SB[(size_t)r * D + col] : 0.f;
        }
    }
#pragma unroll
    for (int it = 0; it < 8; ++it)
        *(ushort8*)(&sw[(t + it * 256) * 8]) = stg[it];
    __syncthreads();

    // GEMM1
#pragma unroll
    for (int nf = 0; nf < 8; ++nf) {
        const int col = nf * 16 + lrow;
#pragma unroll
        for (int kf = 0; kf < 4; ++kf)
            out[nf] = __builtin_amdgcn_mfma_f32_16x16x32_bf16(
                af[kf], ldsB(sw, col, kf * 32 + kb), out[nf], 0, 0, 0);
    }
    __syncthreads();

    // bounce OUT + stage Wt1
#pragma unroll
    for (int it = 0; it < 8; ++it)
        stg[it] = *(const ushort8*)(Wt1 + (t + it * 256) * 8);
#pragma unroll
    for (int nf = 0; nf < 8; ++nf) {
        const int col = nf * 16 + lrow;
#pragma unroll
        for (int i = 0; i < 4; ++i)
            bounce[(w * 16 + rq + i) * 136 + col] = f2bf(out[nf][i]);
    }
#pragma unroll
    for (int it = 0; it < 8; ++it)
        *(ushort8*)(&sw[(t + it * 256) * 8]) = stg[it];
    __syncthreads();

    // GEMM2
    bf16x8 af2[4];
#pragma unroll
    for (int kf = 0; kf < 4; ++kf)
        af2[kf] = *(const bf16x8*)(&bounce[(w * 16 + lrow) * 136 + kb + kf * 32]);
    f32x4 acc2[8];
#pragma unroll
    for (int nf = 0; nf < 8; ++nf) acc2[nf] = (f32x4){0.f, 0.f, 0.f, 0.f};
#pragma unroll
    for (int nf = 0; nf < 8; ++nf) {
        const int col = nf * 16 + lrow;
#pragma unroll
        for (int kf = 0; kf < 4; ++kf)
            acc2[nf] = __builtin_amdgcn_mfma_f32_16x16x32_bf16(
                af2[kf], ldsB(sw, col, kf * 32 + kb), acc2[nf], 0, 0, 0);
    }
    __syncthreads();

    // bounce H1 + stage Wt2
#pragma unroll
    for (int it = 0; it < 8; ++it)
        stg[it] = *(const ushort8*)(Wt2 + (t + it * 256) * 8);
#pragma unroll
    for (int nf = 0; nf < 8; ++nf) {
        const int col = nf * 16 + lrow;
        const float bb = b1[col];
#pragma unroll
        for (int i = 0; i < 4; ++i)
            bounce[(w * 16 + rq + i) * 136 + col] = f2bf(gelu_fast(acc2[nf][i] + bb));
    }
#pragma unroll
    for (int it = 0; it < 8; ++it)
        *(ushort8*)(&sw[(t + it * 256) * 8]) = stg[it];
    __syncthreads();

    // GEMM3 + epilogue
    bf16x8 af3[4];
#pragma unroll
    for (int kf = 0; kf < 4; ++kf)
        af3[kf] = *(const bf16x8*)(&bounce[(w * 16 + lrow) * 136 + kb + kf * 32]);
    f32x4 acc3[8];
#pragma unroll
    for (int nf = 0; nf < 8; ++nf) acc3[nf] = (f32x4){0.f, 0.f, 0.f, 0.f};
#pragma unroll
    for (int nf = 0; nf < 8; ++nf) {
        const int col = nf * 16 + lrow;
#pragma unroll
        for (int kf = 0; kf < 4; ++kf)
            acc3[nf] = __builtin_amdgcn_mfma_f32_16x16x32_bf16(
                af3[kf], ldsB(sw, col, kf * 32 + kb), acc3[nf], 0, 0, 0);
    }
#pragma unroll
    for (int nf = 0; nf < 8; ++nf) {
        const int col = nf * 16 + lrow;
        const float bb = b2[col];
#pragma unroll
        for (int i = 0; i < 4; ++i) {
            int r = row0 + rq + i;
            if (r < N)
                FINAL[(size_t)r * D + col] = out[nf][i] + gelu_fast(acc3[nf][i] + bb);
        }
    }
}

// ---------------------------------------------------------------------------
extern "C" void kernel_launch(void* const* d_in, const int* in_sizes, int n_in,
                              void* d_out, int out_size, void* d_ws, size_t ws_size,
                              hipStream_t stream)
{
    const float* x   = (const float*)d_in[0];
    const int*   EI  = (const int*)  d_in[1];
    const float* EA  = (const float*)d_in[2];
    const float* Wq  = (const float*)d_in[3];
    const float* bq  = (const float*)d_in[4];
    const float* Wk  = (const float*)d_in[5];
    const float* bk  = (const float*)d_in[6];
    const float* Wv  = (const float*)d_in[7];
    const float* bv  = (const float*)d_in[8];
    const float* We  = (const float*)d_in[9];
    const float* Wsk = (const float*)d_in[10];
    const float* bsk = (const float*)d_in[11];
    const float* W1  = (const float*)d_in[12];
    const float* b1  = (const float*)d_in[13];
    const float* W2  = (const float*)d_in[14];
    const float* b2  = (const float*)d_in[15];

    const int N = in_sizes[0] / D;
    const int E = in_sizes[1] / 2;

    char* p = (char*)d_ws;
    auto alloc = [&](size_t bytes) -> void* {
        void* r = (void*)p;
        p += (bytes + 255) & ~(size_t)255;
        return r;
    };
    float*          Sb     = (float*)         alloc((size_t)N * D * 4);   // skip -> preout
    unsigned short* QAb    = (unsigned short*)alloc((size_t)N * 256 * 2); // [Q|QE]
    unsigned short* KVb    = (unsigned short*)alloc((size_t)N * 256 * 2); // [K|V]
    unsigned short* SASb   = (unsigned short*)alloc((size_t)N * D * 2);
    unsigned short* XBb    = (unsigned short*)alloc((size_t)N * D * 2);   // bf16 x
    int2*           SEb    = (int2*)          alloc((size_t)E * 8);
    unsigned short* Wt     = (unsigned short*)alloc((size_t)8 * 16384 * 2);
    float*          bqEb   = (float*)         alloc((size_t)128 * 4);
    int*            deg    = (int*)           alloc((size_t)N * 4);
    int*            rowptr = (int*)           alloc((size_t)(N + 1) * 4);
    int*            cursor = (int*)           alloc((size_t)(N + 1) * 4);
    int*            psums  = (int*)           alloc((size_t)1024 * 4);

    hipMemsetAsync(deg, 0, (size_t)N * sizeof(int), stream);

    const long xtot = (long)N * D;
    const int NB  = (N + 63) / 64;
    const int NB2 = (N + 127) / 128;
    const int EB  = (E + 255) / 256;
    const int XB_ = (int)((xtot + 2047) / 2048);
    const int SB_ = (N + 1023) / 1024;

    prep_kernel<<<513 + EB + XB_, 256, 0, stream>>>(
        Wq, Wk, Wv, Wsk, W1, W2, We, bq, Wt, bqEb, EI, deg, E, EB, x, XBb, xtot);

    scanA<<<SB_, 1024, 0, stream>>>(deg, rowptr, psums, N);
    scanB<<<1, 1024, 0, stream>>>(psums, SB_);
    scanC<<<(N + 255) / 256, 256, 0, stream>>>(rowptr, cursor, psums, N);

    scatter_kernel<<<EB, 256, 0, stream>>>(EI, cursor, SEb, E);

    gemm5<<<5 * NB2, 256, 0, stream>>>(
        XBb, Wt, bq, bk, bv, bsk, bqEb, QAb, KVb, Sb, N, NB2);

    gather_pass<<<(N + 3) / 4, 256, 0, stream>>>(
        rowptr, SEb, EA, QAb, KVb, Sb, SASb, N);

    fused_mlp<<<NB, 256, 0, stream>>>(Sb, SASb,
                                      Wt + (size_t)7 * 16384,
                                      Wt + (size_t)4 * 16384,
                                      Wt + (size_t)5 * 16384,
                                      b1, b2, (float*)d_out, N);
}

// Round 11
// 254.523 us; speedup vs baseline: 1.0990x; 1.0438x over previous
//
#include <hip/hip_runtime.h>
#include <math.h>

// ---------------------------------------------------------------------------
// GraphTransformerBlock: TransformerConv (4 heads x 32) + residual MLP.
// Round 11: gather pipeline deepened to 4 edges per 16-lane group
// (16 edges in flight per wave); all 12 loads of an iteration issue together.
// Everything else unchanged from round 10.
// ---------------------------------------------------------------------------

#define D 128
#define EDIM 32

using bf16x8 = __attribute__((ext_vector_type(8))) short;
using f32x4  = __attribute__((ext_vector_type(4))) float;
using ushort8 = __attribute__((ext_vector_type(8))) unsigned short;

__device__ inline unsigned short f2bf(float f) {
    unsigned int u = __float_as_uint(f);
    u += 0x7FFFu + ((u >> 16) & 1u);          // round-to-nearest-even
    return (unsigned short)(u >> 16);
}
__device__ inline float bf2f(unsigned short h) {
    return __uint_as_float(((unsigned int)h) << 16);
}
__device__ inline float gelu_fast(float x) {
    float x3 = x * x * x;
    float u = 0.7978845608028654f * (x + 0.044715f * x3);
    float t = 1.f - 2.f / (__expf(2.f * u) + 1.f);   // tanh(u)
    return 0.5f * x * (1.f + t);
}
// sum over aligned 4-lane quad via DPP quad_perm (all 4 lanes get the sum)
__device__ inline float quad_add(float x) {
    int a = __builtin_amdgcn_update_dpp(0, __float_as_int(x), 0xB1, 0xF, 0xF, true);
    x += __int_as_float(a);
    a = __builtin_amdgcn_update_dpp(0, __float_as_int(x), 0x4E, 0xF, 0xF, true);
    x += __int_as_float(a);
    return x;
}

// swizzled B-frag read: element (col, kk0..kk0+7) of the staged weight tile
__device__ inline bf16x8 ldsB(const unsigned short* sw, int col, int kk0) {
    return *(const bf16x8*)(sw + col * 128 + (kk0 ^ ((col & 7) << 3)));
}

// ---------------------------------------------------------------------------
// prep: blocks 0..511 -> 8 pre-swizzled bf16 weight tables
//   Wt[m][col*128 + (kk ^ ((col&7)<<3))] = W_m[kk][col]
//   m: 0=Wq 1=Wk 2=Wv 3=Wskip 4=W1 5=W2 6=WqE (inline dot) 7=WtCorr
// block 512: bqE.  blocks 513..513+HB-1: hist. blocks 513+HB..: x -> bf16.
// ---------------------------------------------------------------------------
__global__ __launch_bounds__(256) void prep_kernel(
    const float* __restrict__ Wq, const float* __restrict__ Wk,
    const float* __restrict__ Wv, const float* __restrict__ Wsk,
    const float* __restrict__ W1, const float* __restrict__ W2,
    const float* __restrict__ We, const float* __restrict__ bq,
    unsigned short* __restrict__ Wt, float* __restrict__ bqE,
    const int* __restrict__ EI, int* __restrict__ deg, int E, int HB,
    const float* __restrict__ x, unsigned short* __restrict__ XB, long xtot)
{
    if ((int)blockIdx.x >= 513 + HB) {    // x -> bf16 tail
        long i8 = ((long)(blockIdx.x - 513 - HB) * 256 + threadIdx.x) * 8;
        if (i8 + 8 <= xtot) {
            float4 a = *(const float4*)(x + i8);
            float4 b = *(const float4*)(x + i8 + 4);
            ushort8 u;
            u[0] = f2bf(a.x); u[1] = f2bf(a.y); u[2] = f2bf(a.z); u[3] = f2bf(a.w);
            u[4] = f2bf(b.x); u[5] = f2bf(b.y); u[6] = f2bf(b.z); u[7] = f2bf(b.w);
            *(ushort8*)(XB + i8) = u;
        }
        return;
    }
    if (blockIdx.x >= 513) {              // hist
        int e = (blockIdx.x - 513) * 256 + threadIdx.x;
        if (e < E) atomicAdd(&deg[EI[E + e]], 1);
        return;
    }
    int t = blockIdx.x * 256 + threadIdx.x;
    int m = t >> 14;
    int r = t & 16383;
    if (m >= 8) {                         // bqE block
        if (r < 128) {
            const int hb = r & 96, k = r & 31;
            const float* wek = We + (size_t)k * D + hb;
            float s = 0.f;
#pragma unroll 8
            for (int c = 0; c < 32; ++c) s = fmaf(bq[hb + c], wek[c], s);
            bqE[r] = s;
        }
        return;
    }
    int col = r & 127, kk = r >> 7;
    float v;
    if (m < 6) {
        const float* W = (m == 0) ? Wq : (m == 1) ? Wk : (m == 2) ? Wv
                       : (m == 3) ? Wsk : (m == 4) ? W1 : W2;
        v = W[(size_t)kk * D + col];
    } else if (m == 6) {
        const int hb = col & 96;
        const float* wqr = Wq + (size_t)kk * D + hb;
        const float* wer = We + (size_t)(col & 31) * D + hb;
        float s = 0.f;
#pragma unroll 8
        for (int c = 0; c < 32; ++c) s = fmaf(wqr[c], wer[c], s);
        v = s;
    } else {
        v = ((kk >> 5) == (col >> 5)) ? We[(size_t)(kk & 31) * D + col] : 0.f;
    }
    Wt[(size_t)m * 16384 + (size_t)col * 128 + (kk ^ ((col & 7) << 3))] = f2bf(v);
}

// ---------------------------------------------------------------------------
// hierarchical scan
// ---------------------------------------------------------------------------
__global__ __launch_bounds__(1024) void scanA(
    const int* __restrict__ deg, int* __restrict__ rowptr,
    int* __restrict__ psums, int N)
{
    __shared__ int tmp[1024];
    const int t = threadIdx.x;
    const int i = blockIdx.x * 1024 + t;
    int v = (i < N) ? deg[i] : 0;
    tmp[t] = v;
    __syncthreads();
    for (int off = 1; off < 1024; off <<= 1) {
        int add = (t >= off) ? tmp[t - off] : 0;
        __syncthreads();
        tmp[t] += add;
        __syncthreads();
    }
    if (i < N) rowptr[i + 1] = tmp[t];
    if (t == 1023) psums[blockIdx.x] = tmp[1023];
}

__global__ __launch_bounds__(1024) void scanB(int* __restrict__ psums, int nb)
{
    __shared__ int tmp[1024];
    const int t = threadIdx.x;
    int v = (t < nb) ? psums[t] : 0;
    tmp[t] = v;
    __syncthreads();
    for (int off = 1; off < 1024; off <<= 1) {
        int add = (t >= off) ? tmp[t - off] : 0;
        __syncthreads();
        tmp[t] += add;
        __syncthreads();
    }
    if (t < nb) psums[t] = tmp[t] - v;   // exclusive
}

__global__ __launch_bounds__(256) void scanC(
    int* __restrict__ rowptr, int* __restrict__ cursor,
    const int* __restrict__ psums, int N)
{
    int i = blockIdx.x * 256 + threadIdx.x;
    if (i == 0) { rowptr[0] = 0; cursor[0] = 0; }
    if (i < N) {
        int val = rowptr[i + 1] + psums[i >> 10];
        rowptr[i + 1] = val;
        if (i + 1 < N) cursor[i + 1] = val;
    }
}

// ---------------------------------------------------------------------------
// scatter: (src,eid) int2 per edge into CSR position. No LDS -> full occupancy.
// ---------------------------------------------------------------------------
__global__ __launch_bounds__(256) void scatter_kernel(
    const int* __restrict__ EI, int* __restrict__ cursor,
    int2* __restrict__ SE, int E)
{
    int e = blockIdx.x * 256 + threadIdx.x;
    if (e < E) {
        int dst = EI[E + e];
        int pos = atomicAdd(&cursor[dst], 1);
        SE[pos] = make_int2(EI[e], e);
    }
}

// ---------------------------------------------------------------------------
// gemm5: blockIdx.x = m*NB2 + bx, m=0..4 (Q,K,V,skip,QE). 128-row tiles.
// bf16 outputs (m!=3) are transposed through LDS (re-using sw) so global
// stores are full-line ushort8; skip (m==3) stores f32 directly.
// ---------------------------------------------------------------------------
__global__ __launch_bounds__(256) void gemm5(
    const unsigned short* __restrict__ XB, const unsigned short* __restrict__ Wt,
    const float* __restrict__ bq, const float* __restrict__ bk,
    const float* __restrict__ bv, const float* __restrict__ bs,
    const float* __restrict__ bqE,
    unsigned short* __restrict__ QA, unsigned short* __restrict__ KV,
    float* __restrict__ S, int N, int NB2)
{
    __shared__ unsigned short sw[16384];
    const int t = threadIdx.x;
    const int bid = blockIdx.x;
    const int m = bid / NB2;
    const int bx = bid - m * NB2;
    const int widx = (m < 4) ? m : 6;
    const int lane = t & 63;
    const int w = t >> 6;
    const int row0 = bx * 128 + w * 32;
    const int lrow = lane & 15;
    const int kb = (lane >> 4) * 8;
    const int rq = (lane >> 4) * 4;

    const unsigned short* gsrc = Wt + (size_t)widx * 16384;
    ushort8 stg[8];
#pragma unroll
    for (int it = 0; it < 8; ++it)
        stg[it] = *(const ushort8*)(gsrc + (t + it * 256) * 8);

    bf16x8 af0[4], af1[4];
    {
        int a0 = row0 + lrow;      if (a0 > N - 1) a0 = N - 1;
        int a1 = row0 + 16 + lrow; if (a1 > N - 1) a1 = N - 1;
        const unsigned short* x0 = XB + (size_t)a0 * D + kb;
        const unsigned short* x1 = XB + (size_t)a1 * D + kb;
#pragma unroll
        for (int kf = 0; kf < 4; ++kf) {
            af0[kf] = *(const bf16x8*)(x0 + kf * 32);
            af1[kf] = *(const bf16x8*)(x1 + kf * 32);
        }
    }

#pragma unroll
    for (int it = 0; it < 8; ++it)
        *(ushort8*)(&sw[(t + it * 256) * 8]) = stg[it];
    __syncthreads();

    const float* bias = (m == 0) ? bq : (m == 1) ? bk : (m == 2) ? bv
                      : (m == 3) ? bs : bqE;
    f32x4 acc0[8], acc1[8];
#pragma unroll
    for (int nf = 0; nf < 8; ++nf) {
        acc0[nf] = (f32x4){0.f, 0.f, 0.f, 0.f};
        acc1[nf] = (f32x4){0.f, 0.f, 0.f, 0.f};
    }
#pragma unroll
    for (int nf = 0; nf < 8; ++nf) {
        const int col = nf * 16 + lrow;
#pragma unroll
        for (int kf = 0; kf < 4; ++kf) {
            bf16x8 bfr = ldsB(sw, col, kf * 32 + kb);
            acc0[nf] = __builtin_amdgcn_mfma_f32_16x16x32_bf16(af0[kf], bfr, acc0[nf], 0, 0, 0);
            acc1[nf] = __builtin_amdgcn_mfma_f32_16x16x32_bf16(af1[kf], bfr, acc1[nf], 0, 0, 0);
        }
    }

    if (m == 3) {
        // f32 skip: direct stores (64B-contiguous per (nf,row) segment)
#pragma unroll
        for (int rb = 0; rb < 2; ++rb) {
#pragma unroll
            for (int nf = 0; nf < 8; ++nf) {
                const int col = nf * 16 + lrow;
                const float bb = bias[col];
#pragma unroll
                for (int i = 0; i < 4; ++i) {
                    int r = row0 + rb * 16 + rq + i;
                    if (r < N)
                        S[(size_t)r * D + col] = ((rb == 0) ? acc0[nf][i] : acc1[nf][i]) + bb;
                }
            }
        }
        return;
    }

    // bf16 outputs: bounce through sw (barrier: all MFMA sw-reads are done)
    __syncthreads();
#pragma unroll
    for (int rb = 0; rb < 2; ++rb) {
#pragma unroll
        for (int nf = 0; nf < 8; ++nf) {
            const int col = nf * 16 + lrow;
            const float bb = bias[col];
#pragma unroll
            for (int i = 0; i < 4; ++i)
                sw[(w * 32 + rb * 16 + rq + i) * 128 + col] =
                    f2bf(((rb == 0) ? acc0[nf][i] : acc1[nf][i]) + bb);
        }
    }
    // per-wave patch readback (no cross-wave dependency -> no extra barrier)
    unsigned short* gout = (m == 0) ? QA : (m == 1) ? KV
                         : (m == 2) ? KV + 128 : QA + 128;
#pragma unroll
    for (int it = 0; it < 8; ++it) {
        const int gidx = it * 64 + lane;
        const int row_l = gidx >> 4;          // 0..31
        const int chk = gidx & 15;            // 16B chunk within row
        const int r = row0 + row_l;
        ushort8 vv = *(const ushort8*)(&sw[(w * 32 + row_l) * 128 + chk * 8]);
        if (r < N) *(ushort8*)(gout + (size_t)r * 256 + chk * 8) = vv;
    }
}

// ---------------------------------------------------------------------------
// gather: 1 wave per node; 4 edge groups x 16 lanes (lane owns 8 dims),
// 4 edges per group per iteration (16 edges in flight / wave).
// edge_attr read DIRECTLY (fp32, via eid).
// ---------------------------------------------------------------------------
__global__ __launch_bounds__(256) void gather_pass(
    const int* __restrict__ rowptr, const int2* __restrict__ SE,
    const float* __restrict__ EA,
    const unsigned short* __restrict__ QA, const unsigned short* __restrict__ KV,
    float* __restrict__ SB, unsigned short* __restrict__ SAS, int N)
{
    const int lane = threadIdx.x & 63;
    const int wid = threadIdx.x >> 6;
    const int n = blockIdx.x * 4 + wid;
    if (n >= N) return;
    const int g = lane & 15;        // dim slice: d = g*8..+8 (head g>>2)
    const int grp = lane >> 4;      // edge group 0..3
    const int eoff = (g & 3) * 8;   // this lane's EA slice (floats)

    float q8[8], qe8[8];
    {
        const unsigned short* qa = QA + (size_t)n * 256 + g * 8;
        bf16x8 qb  = *(const bf16x8*)(qa);
        bf16x8 qeb = *(const bf16x8*)(qa + 128);
#pragma unroll
        for (int j = 0; j < 8; ++j) {
            q8[j]  = bf2f((unsigned short)qb[j]);
            qe8[j] = bf2f((unsigned short)qeb[j]);
        }
    }

    float acc[8], sa[8], den = 0.f;
#pragma unroll
    for (int j = 0; j < 8; ++j) { acc[j] = 0.f; sa[j] = 0.f; }

    const int i0 = rowptr[n], i1 = rowptr[n + 1];

    int2 se[4];
#pragma unroll
    for (int u = 0; u < 4; ++u) {
        int ii = i0 + grp + u * 4;
        se[u] = (ii < i1) ? SE[ii] : make_int2(-1, 0);
    }

    for (int base = i0; base < i1; base += 16) {
        // issue all 12 data loads for the 4 in-flight edges
        bf16x8 kS[4], vS[4];
        float4 e0S[4], e1S[4];
#pragma unroll
        for (int u = 0; u < 4; ++u) {
            kS[u] = (bf16x8){0,0,0,0,0,0,0,0};
            vS[u] = kS[u];
            e0S[u] = (float4){0.f,0.f,0.f,0.f};
            e1S[u] = e0S[u];
            if (se[u].x >= 0) {
                const unsigned short* kv = KV + (size_t)se[u].x * 256 + g * 8;
                kS[u] = *(const bf16x8*)(kv);
                vS[u] = *(const bf16x8*)(kv + 128);
                const float* ear = EA + (size_t)se[u].y * EDIM + eoff;
                e0S[u] = *(const float4*)(ear);
                e1S[u] = *(const float4*)(ear + 4);
            }
        }
        // prefetch next iteration's (src,eid) pairs
        int2 seN[4];
#pragma unroll
        for (int u = 0; u < 4; ++u) {
            int ii = base + 16 + grp + u * 4;
            seN[u] = (ii < i1) ? SE[ii] : make_int2(-1, 0);
        }
        // compute the 4 edges
#pragma unroll
        for (int u = 0; u < 4; ++u) {
            float ef[8] = {e0S[u].x, e0S[u].y, e0S[u].z, e0S[u].w,
                           e1S[u].x, e1S[u].y, e1S[u].z, e1S[u].w};
            float p = 0.f;
#pragma unroll
            for (int j = 0; j < 8; ++j)
                p = fmaf(q8[j], bf2f((unsigned short)kS[u][j]),
                         fmaf(ef[j], qe8[j], p));
            p = quad_add(p);
            const float ex = (se[u].x >= 0) ? __expf(p * 0.17677669529663689f) : 0.f;
            den += ex;
#pragma unroll
            for (int j = 0; j < 8; ++j) {
                acc[j] = fmaf(ex, bf2f((unsigned short)vS[u][j]), acc[j]);
                sa[j]  = fmaf(ex, ef[j], sa[j]);
            }
        }
#pragma unroll
        for (int u = 0; u < 4; ++u) se[u] = seN[u];
    }

    // combine the 4 edge groups (once per node)
#pragma unroll
    for (int off = 16; off <= 32; off <<= 1) {
        den += __shfl_xor(den, off, 64);
#pragma unroll
        for (int j = 0; j < 8; ++j) {
            acc[j] += __shfl_xor(acc[j], off, 64);
            sa[j]  += __shfl_xor(sa[j],  off, 64);
        }
    }

    if (grp == 0) {
        const float rden = 1.f / (den + 1e-16f);
        float* so = SB + (size_t)n * D + g * 8;
        unsigned short* po = SAS + (size_t)n * D + g * 8;
#pragma unroll
        for (int j = 0; j < 8; ++j) {
            so[j] = fmaf(acc[j], rden, so[j]);    // + skip (in place)
            po[j] = f2bf(sa[j] * rden);
        }
    }
}

// ---------------------------------------------------------------------------
// fused_mlp: OUT = preout + SAS @ WtCorr; H1 = gelu(OUT@W1+b1);
//            FINAL = OUT + gelu(H1@W2+b2).
// ---------------------------------------------------------------------------
__global__ __launch_bounds__(256) void fused_mlp(
    const float* __restrict__ SB, const unsigned short* __restrict__ SAS,
    const unsigned short* __restrict__ WtC, const unsigned short* __restrict__ Wt1,
    const unsigned short* __restrict__ Wt2,
    const float* __restrict__ b1, const float* __restrict__ b2,
    float* __restrict__ FINAL, int N)
{
    __shared__ unsigned short sw[16384];
    __shared__ unsigned short bounce[64 * 136];
    const int t = threadIdx.x;
    const int lane = t & 63;
    const int w = t >> 6;
    const int row0 = blockIdx.x * 64 + w * 16;
    const int lrow = lane & 15;
    const int kb = (lane >> 4) * 8;
    const int rq = (lane >> 4) * 4;

    ushort8 stg[8];
#pragma unroll
    for (int it = 0; it < 8; ++it)
        stg[it] = *(const ushort8*)(WtC + (t + it * 256) * 8);

    bf16x8 af[4];
    {
        int ar = row0 + lrow; if (ar > N - 1) ar = N - 1;
        const unsigned short* xr = SAS + (size_t)ar * D + kb;
#pragma unroll
        for (int kf = 0; kf < 4; ++kf) af[kf] = *(const bf16x8*)(xr + kf * 32);
    }
    f32x4 out[8];
#pragma unroll
    for (int nf = 0; nf < 8; ++nf) {
        const int col = nf * 16 + lrow;
#pragma unroll
        for (int i = 0; i < 4; ++i) {
            int r = row0 + rq + i;
            out[nf][i] = (r < N) ? SB[(size_t)r * D + col] : 0.f;
        }
    }
#pragma unroll
    for (int it = 0; it < 8; ++it)
        *(ushort8*)(&sw[(t + it * 256) * 8]) = stg[it];
    __syncthreads();

    // GEMM1
#pragma unroll
    for (int nf = 0; nf < 8; ++nf) {
        const int col = nf * 16 + lrow;
#pragma unroll
        for (int kf = 0; kf < 4; ++kf)
            out[nf] = __builtin_amdgcn_mfma_f32_16x16x32_bf16(
                af[kf], ldsB(sw, col, kf * 32 + kb), out[nf], 0, 0, 0);
    }
    __syncthreads();

    // bounce OUT + stage Wt1
#pragma unroll
    for (int it = 0; it < 8; ++it)
        stg[it] = *(const ushort8*)(Wt1 + (t + it * 256) * 8);
#pragma unroll
    for (int nf = 0; nf < 8; ++nf) {
        const int col = nf * 16 + lrow;
#pragma unroll
        for (int i = 0; i < 4; ++i)
            bounce[(w * 16 + rq + i) * 136 + col] = f2bf(out[nf][i]);
    }
#pragma unroll
    for (int it = 0; it < 8; ++it)
        *(ushort8*)(&sw[(t + it * 256) * 8]) = stg[it];
    __syncthreads();

    // GEMM2
    bf16x8 af2[4];
#pragma unroll
    for (int kf = 0; kf < 4; ++kf)
        af2[kf] = *(const bf16x8*)(&bounce[(w * 16 + lrow) * 136 + kb + kf * 32]);
    f32x4 acc2[8];
#pragma unroll
    for (int nf = 0; nf < 8; ++nf) acc2[nf] = (f32x4){0.f, 0.f, 0.f, 0.f};
#pragma unroll
    for (int nf = 0; nf < 8; ++nf) {
        const int col = nf * 16 + lrow;
#pragma unroll
        for (int kf = 0; kf < 4; ++kf)
            acc2[nf] = __builtin_amdgcn_mfma_f32_16x16x32_bf16(
                af2[kf], ldsB(sw, col, kf * 32 + kb), acc2[nf], 0, 0, 0);
    }
    __syncthreads();

    // bounce H1 + stage Wt2
#pragma unroll
    for (int it = 0; it < 8; ++it)
        stg[it] = *(const ushort8*)(Wt2 + (t + it * 256) * 8);
#pragma unroll
    for (int nf = 0; nf < 8; ++nf) {
        const int col = nf * 16 + lrow;
        const float bb = b1[col];
#pragma unroll
        for (int i = 0; i < 4; ++i)
            bounce[(w * 16 + rq + i) * 136 + col] = f2bf(gelu_fast(acc2[nf][i] + bb));
    }
#pragma unroll
    for (int it = 0; it < 8; ++it)
        *(ushort8*)(&sw[(t + it * 256) * 8]) = stg[it];
    __syncthreads();

    // GEMM3 + epilogue
    bf16x8 af3[4];
#pragma unroll
    for (int kf = 0; kf < 4; ++kf)
        af3[kf] = *(const bf16x8*)(&bounce[(w * 16 + lrow) * 136 + kb + kf * 32]);
    f32x4 acc3[8];
#pragma unroll
    for (int nf = 0; nf < 8; ++nf) acc3[nf] = (f32x4){0.f, 0.f, 0.f, 0.f};
#pragma unroll
    for (int nf = 0; nf < 8; ++nf) {
        const int col = nf * 16 + lrow;
#pragma unroll
        for (int kf = 0; kf < 4; ++kf)
            acc3[nf] = __builtin_amdgcn_mfma_f32_16x16x32_bf16(
                af3[kf], ldsB(sw, col, kf * 32 + kb), acc3[nf], 0, 0, 0);
    }
#pragma unroll
    for (int nf = 0; nf < 8; ++nf) {
        const int col = nf * 16 + lrow;
        const float bb = b2[col];
#pragma unroll
        for (int i = 0; i < 4; ++i) {
            int r = row0 + rq + i;
            if (r < N)
                FINAL[(size_t)r * D + col] = out[nf][i] + gelu_fast(acc3[nf][i] + bb);
        }
    }
}

// ---------------------------------------------------------------------------
extern "C" void kernel_launch(void* const* d_in, const int* in_sizes, int n_in,
                              void* d_out, int out_size, void* d_ws, size_t ws_size,
                              hipStream_t stream)
{
    const float* x   = (const float*)d_in[0];
    const int*   EI  = (const int*)  d_in[1];
    const float* EA  = (const float*)d_in[2];
    const float* Wq  = (const float*)d_in[3];
    const float* bq  = (const float*)d_in[4];
    const float* Wk  = (const float*)d_in[5];
    const float* bk  = (const float*)d_in[6];
    const float* Wv  = (const float*)d_in[7];
    const float* bv  = (const float*)d_in[8];
    const float* We  = (const float*)d_in[9];
    const float* Wsk = (const float*)d_in[10];
    const float* bsk = (const float*)d_in[11];
    const float* W1  = (const float*)d_in[12];
    const float* b1  = (const float*)d_in[13];
    const float* W2  = (const float*)d_in[14];
    const float* b2  = (const float*)d_in[15];

    const int N = in_sizes[0] / D;
    const int E = in_sizes[1] / 2;

    char* p = (char*)d_ws;
    auto alloc = [&](size_t bytes) -> void* {
        void* r = (void*)p;
        p += (bytes + 255) & ~(size_t)255;
        return r;
    };
    float*          Sb     = (float*)         alloc((size_t)N * D * 4);   // skip -> preout
    unsigned short* QAb    = (unsigned short*)alloc((size_t)N * 256 * 2); // [Q|QE]
    unsigned short* KVb    = (unsigned short*)alloc((size_t)N * 256 * 2); // [K|V]
    unsigned short* SASb   = (unsigned short*)alloc((size_t)N * D * 2);
    unsigned short* XBb    = (unsigned short*)alloc((size_t)N * D * 2);   // bf16 x
    int2*           SEb    = (int2*)          alloc((size_t)E * 8);
    unsigned short* Wt     = (unsigned short*)alloc((size_t)8 * 16384 * 2);
    float*          bqEb   = (float*)         alloc((size_t)128 * 4);
    int*            deg    = (int*)           alloc((size_t)N * 4);
    int*            rowptr = (int*)           alloc((size_t)(N + 1) * 4);
    int*            cursor = (int*)           alloc((size_t)(N + 1) * 4);
    int*            psums  = (int*)           alloc((size_t)1024 * 4);

    hipMemsetAsync(deg, 0, (size_t)N * sizeof(int), stream);

    const long xtot = (long)N * D;
    const int NB  = (N + 63) / 64;
    const int NB2 = (N + 127) / 128;
    const int EB  = (E + 255) / 256;
    const int XB_ = (int)((xtot + 2047) / 2048);
    const int SB_ = (N + 1023) / 1024;

    prep_kernel<<<513 + EB + XB_, 256, 0, stream>>>(
        Wq, Wk, Wv, Wsk, W1, W2, We, bq, Wt, bqEb, EI, deg, E, EB, x, XBb, xtot);

    scanA<<<SB_, 1024, 0, stream>>>(deg, rowptr, psums, N);
    scanB<<<1, 1024, 0, stream>>>(psums, SB_);
    scanC<<<(N + 255) / 256, 256, 0, stream>>>(rowptr, cursor, psums, N);

    scatter_kernel<<<EB, 256, 0, stream>>>(EI, cursor, SEb, E);

    gemm5<<<5 * NB2, 256, 0, stream>>>(
        XBb, Wt, bq, bk, bv, bsk, bqEb, QAb, KVb, Sb, N, NB2);

    gather_pass<<<(N + 3) / 4, 256, 0, stream>>>(
        rowptr, SEb, EA, QAb, KVb, Sb, SASb, N);

    fused_mlp<<<NB, 256, 0, stream>>>(Sb, SASb,
                                      Wt + (size_t)7 * 16384,
                                      Wt + (size_t)4 * 16384,
                                      Wt + (size_t)5 * 16384,
                                      b1, b2, (float*)d_out, N);
}